// Round 2
// baseline (202.974 us; speedup 1.0000x reference)
//
#include <hip/hip_runtime.h>
#include <math.h>

// EvidNets fused kernel.
// Closed form replaces the lax.scan:
//   A_c(b) = prod_k (1 - s_kb * (1 - U_kc)),  N(b) = prod_k (1 - s_kb)
//   out[b][c<20] = (A_c - N)/K,  out[b][20] = N/K,  K = sum_c A_c - 19*N
// where s_kb = alphap_k * exp(-gamma_k^2 * (0.5*(|W_k|^2 + |x_b|^2) - W_k.x_b)).

#define NBATCH 16384
#define ND     256
#define NP     512
#define NCLS   20
#define OC     21            // NCLS + 1
#define TB     64            // samples per block
#define TK     64            // prototypes per chunk
#define NCHUNK (NP / TK)     // 8
#define DSL    64            // d-slice width
#define NSLICE (ND / DSL)    // 4
#define NT     256
#define LDX    68            // padded LDS row stride (words), 16B-aligned rows

__device__ __forceinline__ void fma4(const float4 a, const float4 b, float& d) {
  d = fmaf(a.x, b.x, d); d = fmaf(a.y, b.y, d);
  d = fmaf(a.z, b.z, d); d = fmaf(a.w, b.w, d);
}

__global__ __launch_bounds__(NT)
void evid_fused(const float* __restrict__ X, const float* __restrict__ Wm,
                const float* __restrict__ BETA, const float* __restrict__ ALPHA,
                const float* __restrict__ GAMMA, float* __restrict__ OUT)
{
  __shared__ __align__(16) float xs [DSL][LDX];   // xs[b_local][dd]
  __shared__ __align__(16) float wsh[DSL][LDX];   // wsh[k_local][dd]
  __shared__ __align__(16) float ss [TK][LDX];    // ss[kk][b]  (k-major for combine reads)
  __shared__ __align__(16) float vs [OC][LDX];    // vs[c][kk] = 1 - U[k0+kk][c]; vs[20][kk] = 1
  __shared__ float xq[TB], wq[TK], apch[TK], g2ch[TK];
  __shared__ float redx[4][TB], redw[4][TK];

  const int t     = threadIdx.x;
  const int bbase = blockIdx.x * TB;
  const int tb    = t & 15;        // microtile sample lane (b_i = tb + 16*i)
  const int tk    = t >> 4;        // microtile proto lane  (k_j = tk + 16*j)
  const int srow  = t >> 4;        // staging row 0..15
  const int sdq   = t & 15;        // staging float4 index 0..15
  const int cb    = t & 63;        // combine: sample
  const int part  = t >> 6;        // combine: which 16-k quarter

  float Ap[OC];
  #pragma unroll
  for (int c = 0; c < OC; ++c) Ap[c] = 1.0f;

  float xqacc = 0.0f;

  for (int chunk = 0; chunk < NCHUNK; ++chunk) {
    const int k0 = chunk * TK;
    __syncthreads();                              // prev combine done: vs/ss/apch reusable
    if (t < TK) {
      const int k = k0 + t;
      float bsum = 0.0f;
      #pragma unroll
      for (int c = 0; c < NCLS; ++c) { const float bv = BETA[k*NCLS + c]; bsum = fmaf(bv, bv, bsum); }
      const float binv = 1.0f / bsum;
      #pragma unroll
      for (int c = 0; c < NCLS; ++c) { const float bv = BETA[k*NCLS + c]; vs[c][t] = 1.0f - bv*bv*binv; }
      vs[NCLS][t] = 1.0f;
      apch[t] = 0.99f / (1.0f + expf(-ALPHA[k]));
      const float gv = GAMMA[k];
      g2ch[t] = gv * gv;
    }

    float acc[4][4] = {};
    float wqacc = 0.0f;

    for (int sl = 0; sl < NSLICE; ++sl) {
      const int d0 = sl * DSL;
      __syncthreads();                            // prev slice's GEMM reads done
      #pragma unroll
      for (int p = 0; p < 4; ++p) {
        const int r = srow + 16*p;
        *(float4*)&xs [r][4*sdq] = *(const float4*)&X [(size_t)(bbase + r)*ND + d0 + 4*sdq];
        *(float4*)&wsh[r][4*sdq] = *(const float4*)&Wm[(size_t)(k0    + r)*ND + d0 + 4*sdq];
      }
      __syncthreads();                            // staging visible

      // row-sum-of-squares partials (each thread covers a 16-wide d quarter)
      #pragma unroll
      for (int m = 0; m < 4; ++m) {
        const float4 v = *(const float4*)&wsh[cb][part*16 + 4*m];
        wqacc = fmaf(v.x,v.x, fmaf(v.y,v.y, fmaf(v.z,v.z, fmaf(v.w,v.w, wqacc))));
      }
      if (chunk == 0) {
        #pragma unroll
        for (int m = 0; m < 4; ++m) {
          const float4 v = *(const float4*)&xs[cb][part*16 + 4*m];
          xqacc = fmaf(v.x,v.x, fmaf(v.y,v.y, fmaf(v.z,v.z, fmaf(v.w,v.w, xqacc))));
        }
      }

      // 4x4 strided-microtile f32 GEMM over this d-slice
      #pragma unroll
      for (int dq = 0; dq < 16; ++dq) {
        const float4 xa0 = *(const float4*)&xs [tb +  0][4*dq];
        const float4 xa1 = *(const float4*)&xs [tb + 16][4*dq];
        const float4 xa2 = *(const float4*)&xs [tb + 32][4*dq];
        const float4 xa3 = *(const float4*)&xs [tb + 48][4*dq];
        const float4 wb0 = *(const float4*)&wsh[tk +  0][4*dq];
        const float4 wb1 = *(const float4*)&wsh[tk + 16][4*dq];
        const float4 wb2 = *(const float4*)&wsh[tk + 32][4*dq];
        const float4 wb3 = *(const float4*)&wsh[tk + 48][4*dq];
        fma4(xa0, wb0, acc[0][0]); fma4(xa0, wb1, acc[0][1]); fma4(xa0, wb2, acc[0][2]); fma4(xa0, wb3, acc[0][3]);
        fma4(xa1, wb0, acc[1][0]); fma4(xa1, wb1, acc[1][1]); fma4(xa1, wb2, acc[1][2]); fma4(xa1, wb3, acc[1][3]);
        fma4(xa2, wb0, acc[2][0]); fma4(xa2, wb1, acc[2][1]); fma4(xa2, wb2, acc[2][2]); fma4(xa2, wb3, acc[2][3]);
        fma4(xa3, wb0, acc[3][0]); fma4(xa3, wb1, acc[3][1]); fma4(xa3, wb2, acc[3][2]); fma4(xa3, wb3, acc[3][3]);
      }
    }

    redw[part][cb] = wqacc;
    if (chunk == 0) redx[part][cb] = xqacc;
    __syncthreads();
    if (t < TK) {
      wq[t] = redw[0][t] + redw[1][t] + redw[2][t] + redw[3][t];
      if (chunk == 0) xq[t] = redx[0][t] + redx[1][t] + redx[2][t] + redx[3][t];
    }
    __syncthreads();                              // wq/xq/apch/g2ch ready

    // s = alphap * exp(-g2 * (0.5*(wsq + xsq) - dot)), written k-major
    #pragma unroll
    for (int j = 0; j < 4; ++j) {
      const int kj = tk + 16*j;
      const float wqk = wq[kj], ap = apch[kj], g2 = g2ch[kj];
      #pragma unroll
      for (int i = 0; i < 4; ++i) {
        const int bi = tb + 16*i;
        const float dval = 0.5f*(wqk + xq[bi]) - acc[i][j];
        ss[kj][bi] = ap * expf(-g2 * dval);
      }
    }
    __syncthreads();                              // ss ready

    // combine: thread (cb, part) folds its 16 k's into 21 running products
    {
      float sv[16];
      #pragma unroll
      for (int m = 0; m < 16; ++m) sv[m] = ss[16*part + m][cb];
      #pragma unroll
      for (int c = 0; c < OC; ++c) {
        float a = Ap[c];
        #pragma unroll
        for (int mq = 0; mq < 4; ++mq) {
          const float4 vv = *(const float4*)&vs[c][16*part + 4*mq];
          const float t0 = fmaf(-sv[4*mq+0], vv.x, 1.0f);
          const float t1 = fmaf(-sv[4*mq+1], vv.y, 1.0f);
          const float t2 = fmaf(-sv[4*mq+2], vv.z, 1.0f);
          const float t3 = fmaf(-sv[4*mq+3], vv.w, 1.0f);
          a = a * ((t0*t1)*(t2*t3));
        }
        Ap[c] = a;
      }
    }
  }

  // cross-part product reduction (4 partials per (b,c)) via ss, then output
  __syncthreads();
  if (part >= 2) {
    #pragma unroll
    for (int c = 0; c < OC; ++c) ss[(part-2)*OC + c][cb] = Ap[c];
  }
  __syncthreads();
  if (part < 2) {
    #pragma unroll
    for (int c = 0; c < OC; ++c) Ap[c] *= ss[part*OC + c][cb];
  }
  __syncthreads();
  if (part == 1) {
    #pragma unroll
    for (int c = 0; c < OC; ++c) ss[c][cb] = Ap[c];
  }
  __syncthreads();
  if (part == 0) {
    #pragma unroll
    for (int c = 0; c < OC; ++c) Ap[c] *= ss[c][cb];
    const float Nv = Ap[NCLS];
    float Ks = Nv;
    #pragma unroll
    for (int c = 0; c < NCLS; ++c) Ks += Ap[c] - Nv;
    const float invk = 1.0f / Ks;
    #pragma unroll
    for (int c = 0; c < NCLS; ++c) ss[c][cb] = (Ap[c] - Nv) * invk;
    ss[NCLS][cb] = Nv * invk;
  }
  __syncthreads();
  for (int idx = t; idx < TB*OC; idx += NT) {
    const int b = idx / OC;
    const int c = idx - b*OC;
    OUT[(size_t)bbase*OC + idx] = ss[c][b];
  }
}

extern "C" void kernel_launch(void* const* d_in, const int* in_sizes, int n_in,
                              void* d_out, int out_size, void* d_ws, size_t ws_size,
                              hipStream_t stream) {
  (void)in_sizes; (void)n_in; (void)d_ws; (void)ws_size; (void)out_size;
  const float* X     = (const float*)d_in[0];
  const float* Wm    = (const float*)d_in[1];
  const float* BETA  = (const float*)d_in[2];
  const float* ALPHA = (const float*)d_in[3];
  const float* GAMMA = (const float*)d_in[4];
  float* OUT = (float*)d_out;
  hipLaunchKernelGGL(evid_fused, dim3(NBATCH/TB), dim3(NT), 0, stream,
                     X, Wm, BETA, ALPHA, GAMMA, OUT);
}

// Round 4
// 168.857 us; speedup vs baseline: 1.2020x; 1.2020x over previous
//
#include <hip/hip_runtime.h>
#include <math.h>

// EvidNets fused, MFMA bf16x2 version.
// Closed form replaces the lax.scan:
//   A_c(b) = prod_k (1 - s_kb * (1 - U_kc)),  N(b) = prod_k (1 - s_kb)
//   out[b][c<20] = (A_c - N)/K,  out[b][20] = N/K,  K = sum_c A_c - 19*N
//   s_kb = alphap_k * exp(-gamma_k^2 * (0.5*(|W_k|^2 + |x_b|^2) - W_k.x_b))
// GEMM W@X^T done with v_mfma_f32_32x32x16_bf16 on a hi/lo bf16 split of both
// operands (3 MFMAs per k-step: hh + hl + lh), accuracy ~= f32.
// Pre-pass packs X,W into MFMA fragment order in d_ws so staging is pure copy.

#define NBATCH 16384
#define ND     256
#define NP     512
#define NCLS   20
#define OC     21

typedef short  short8  __attribute__((ext_vector_type(8)));
typedef unsigned short ushort8 __attribute__((ext_vector_type(8)));
typedef float  f32x16  __attribute__((ext_vector_type(16)));

// ---- workspace layout (bytes), all offsets 16B-aligned ----
#define OFF_PXH 0u
#define OFF_PXL (8u*1024u*1024u)
#define OFF_PWH (16u*1024u*1024u)
#define OFF_PWL (OFF_PWH + 256u*1024u)
#define OFF_XQ  (OFF_PWL + 256u*1024u)
#define OFF_WQ  (OFF_XQ + 64u*1024u)
#define OFF_APH (OFF_WQ + 2048u)
#define OFF_G2A (OFF_APH + 2048u)
#define WS_NEED ((size_t)(OFF_G2A + 2048u))

__device__ __forceinline__ unsigned short f2bf_rn(float f) {
  unsigned int u = __float_as_uint(f);
  unsigned int r = (u + 0x7FFFu + ((u >> 16) & 1u)) >> 16;   // RNE (finite inputs)
  return (unsigned short)r;
}
__device__ __forceinline__ float bf2f(unsigned short h) {
  return __uint_as_float(((unsigned int)h) << 16);
}

// Pack rows of src[nrows][256] f32 into MFMA fragment order (hi/lo bf16) and
// row sum-of-squares. Fragment order: elem (tile,step,lane,j) = src[tile*32 +
// (lane&31)][step*16 + 8*(lane>>5) + j]  -> flat ((tile*16+step)*64+lane)*8+j.
__global__ __launch_bounds__(256)
void convert_pack(const float* __restrict__ src, unsigned short* __restrict__ dh,
                  unsigned short* __restrict__ dl, float* __restrict__ sq, int nrows)
{
  const int tid = blockIdx.x * 256 + threadIdx.x;
  const int row = tid >> 5, seg = tid & 31;
  if (row >= nrows) return;
  const float4* s4 = (const float4*)(src + (size_t)row * ND + seg * 8);
  const float4 a = s4[0], b = s4[1];
  const float v[8] = {a.x, a.y, a.z, a.w, b.x, b.y, b.z, b.w};
  ushort8 hv, lv;
  float ssq = 0.f;
  #pragma unroll
  for (int j = 0; j < 8; ++j) {
    ssq = fmaf(v[j], v[j], ssq);
    const unsigned short hh = f2bf_rn(v[j]);
    hv[j] = hh;
    lv[j] = f2bf_rn(v[j] - bf2f(hh));
  }
  const int tile = row >> 5, m = row & 31, step = seg >> 1, r = seg & 1;
  const size_t cidx = (size_t)(tile * 16 + step) * 64 + m + 32 * r;
  *(ushort8*)(dh + cidx * 8) = hv;
  *(ushort8*)(dl + cidx * 8) = lv;
  #pragma unroll
  for (int off = 1; off < 32; off <<= 1) ssq += __shfl_xor(ssq, off, 64);
  if (seg == 0) sq[row] = ssq;
}

__global__ __launch_bounds__(256)
void prep_scalars(const float* __restrict__ alpha, const float* __restrict__ gamma,
                  float* __restrict__ APH, float* __restrict__ G2A)
{
  const int p = blockIdx.x * 256 + threadIdx.x;
  if (p < NP) {
    APH[p] = 0.99f / (1.f + __expf(-alpha[p]));
    const float g = gamma[p];
    G2A[p] = g * g;
  }
}

// Main fused kernel: 512 blocks x 256 threads. TB=32 samples/block; 4 waves,
// wave w owns a 32x32 (b x p) MFMA tile; TK=128 protos/chunk, 4 chunks.
__global__ __launch_bounds__(256, 2)
void evid_mfma(const unsigned short* __restrict__ PXH, const unsigned short* __restrict__ PXL,
               const unsigned short* __restrict__ PWH, const unsigned short* __restrict__ PWL,
               const float* __restrict__ XQ, const float* __restrict__ WQ,
               const float* __restrict__ APH, const float* __restrict__ G2A,
               const float* __restrict__ BETA, float* __restrict__ OUT)
{
  __shared__ __align__(16) unsigned short Ah[8192], Al[8192];  // 16 steps x 64 lanes x 8 bf16
  __shared__ float ss[128 * 33];          // s[p_local][b], stride 33 (conflict-free)
  __shared__ float vsd[OC * 128];         // vsd[c][k_local] = 1-U (row 20 = 1)
  __shared__ float xqs[32], wqs[128], aps[128], g2s[128];

  const int t    = threadIdx.x;
  const int lane = t & 63, wave = t >> 6;
  const int tile = blockIdx.x;

  { // stage resident A fragments (one PX tile = 16 KB hi + 16 KB lo)
    const float4* sH = (const float4*)(PXH + (size_t)tile * 8192);
    const float4* sL = (const float4*)(PXL + (size_t)tile * 8192);
    float4* dH = (float4*)Ah; float4* dL = (float4*)Al;
    #pragma unroll
    for (int i = 0; i < 4; ++i) { dH[i*256 + t] = sH[i*256 + t]; dL[i*256 + t] = sL[i*256 + t]; }
    if (t < 32) xqs[t] = XQ[tile * 32 + t];
  }

  float Ap[OC];
  #pragma unroll
  for (int c = 0; c < OC; ++c) Ap[c] = 1.0f;
  __syncthreads();

  for (int chunk = 0; chunk < 4; ++chunk) {
    __syncthreads();   // prev combine's reads of ss/vsd done

    if (t < 128) {     // per-chunk prototype params
      const int k = chunk * 128 + t;
      float bv[NCLS], bs = 0.f;
      #pragma unroll
      for (int c = 0; c < NCLS; ++c) { bv[c] = BETA[k * NCLS + c]; bs = fmaf(bv[c], bv[c], bs); }
      const float binv = 1.f / bs;
      #pragma unroll
      for (int c = 0; c < NCLS; ++c) vsd[c * 128 + t] = 1.f - bv[c] * bv[c] * binv;
      vsd[NCLS * 128 + t] = 1.f;
      wqs[t] = WQ[k]; aps[t] = APH[k]; g2s[t] = G2A[k];
    }

    // MFMA: acc[m=sample 32][n=proto 32] over K=256, 3 passes (hh, hl, lh)
    f32x16 acc;
    #pragma unroll
    for (int i = 0; i < 16; ++i) acc[i] = 0.f;
    const int ptile = chunk * 4 + wave;
    const short8* bH = (const short8*)PWH + (size_t)ptile * 16 * 64 + lane;
    const short8* bL = (const short8*)PWL + (size_t)ptile * 16 * 64 + lane;
    const short8* aH = (const short8*)Ah + lane;
    const short8* aL = (const short8*)Al + lane;
    #pragma unroll
    for (int step = 0; step < 16; ++step) {
      const short8 ah = aH[step * 64], al = aL[step * 64];
      const short8 bh = bH[step * 64], bl = bL[step * 64];
      acc = __builtin_amdgcn_mfma_f32_32x32x16_bf16(ah, bh, acc, 0, 0, 0);
      acc = __builtin_amdgcn_mfma_f32_32x32x16_bf16(ah, bl, acc, 0, 0, 0);
      acc = __builtin_amdgcn_mfma_f32_32x32x16_bf16(al, bh, acc, 0, 0, 0);
    }
    __syncthreads();   // params visible

    // epilogue: s = alphap * exp(-g2 * (0.5*(wq+xq) - dot)); C/D layout:
    // col(n) = lane&31, row(m) = (reg&3) + 8*(reg>>2) + 4*(lane>>5)
    {
      const int   pl  = wave * 32 + (lane & 31);
      const float wqk = wqs[pl], apk = aps[pl], g2k = g2s[pl];
      const int   rb  = 4 * (lane >> 5);
      #pragma unroll
      for (int rg = 0; rg < 16; ++rg) {
        const int   m  = (rg & 3) + 8 * (rg >> 2) + rb;
        const float dv = 0.5f * (wqk + xqs[m]) - acc[rg];
        ss[pl * 33 + m] = apk * __expf(-g2k * dv);
      }
    }
    __syncthreads();   // ss ready

    // combine: thread (cb = t&31, part = t>>5 of 8) folds 16 k's into Ap[21]
    {
      const int cb = t & 31, part = t >> 5;
      float sv[16];
      #pragma unroll
      for (int i = 0; i < 16; ++i) sv[i] = ss[(part * 16 + i) * 33 + cb];
      #pragma unroll
      for (int c = 0; c < OC; ++c) {
        const float* vc = &vsd[c * 128 + part * 16];
        float a = Ap[c];
        #pragma unroll
        for (int q = 0; q < 4; ++q) {
          const float t0 = fmaf(-sv[4*q+0], vc[4*q+0], 1.0f);
          const float t1 = fmaf(-sv[4*q+1], vc[4*q+1], 1.0f);
          const float t2 = fmaf(-sv[4*q+2], vc[4*q+2], 1.0f);
          const float t3 = fmaf(-sv[4*q+3], vc[4*q+3], 1.0f);
          a = a * ((t0 * t1) * (t2 * t3));
        }
        Ap[c] = a;
      }
    }
  }

  // cross-part product reduction (8 partials per (b,c)), then normalize+store
  const int cb = t & 31, part = t >> 5;
  __syncthreads();
  if (part >= 4) {
    #pragma unroll
    for (int c = 0; c < OC; ++c) ss[((part - 4) * OC + c) * 33 + cb] = Ap[c];
  }
  __syncthreads();
  if (part < 4) {
    #pragma unroll
    for (int c = 0; c < OC; ++c) Ap[c] *= ss[(part * OC + c) * 33 + cb];
  }
  __syncthreads();
  if (part >= 2 && part < 4) {
    #pragma unroll
    for (int c = 0; c < OC; ++c) ss[((part - 2) * OC + c) * 33 + cb] = Ap[c];
  }
  __syncthreads();
  if (part < 2) {
    #pragma unroll
    for (int c = 0; c < OC; ++c) Ap[c] *= ss[(part * OC + c) * 33 + cb];
  }
  __syncthreads();
  if (part == 1) {
    #pragma unroll
    for (int c = 0; c < OC; ++c) ss[c * 33 + cb] = Ap[c];
  }
  __syncthreads();
  if (part == 0) {
    #pragma unroll
    for (int c = 0; c < OC; ++c) Ap[c] *= ss[c * 33 + cb];
    const float Nv = Ap[NCLS];
    float Ks = Nv;
    #pragma unroll
    for (int c = 0; c < NCLS; ++c) Ks += Ap[c] - Nv;
    const float invk = 1.0f / Ks;
    #pragma unroll
    for (int c = 0; c < NCLS; ++c) ss[c * 33 + cb] = (Ap[c] - Nv) * invk;
    ss[NCLS * 33 + cb] = Nv * invk;
  }
  __syncthreads();
  for (int idx = t; idx < 32 * OC; idx += 256) {
    const int b = idx / OC, c = idx - b * OC;
    OUT[(size_t)tile * 32 * OC + idx] = ss[c * 33 + b];
  }
}

// ---------------- fallback (verified f32 path, used if ws too small) ----------------
#define TBF 64
#define TKF 64
#define DSL 64
#define LDX 68

__device__ __forceinline__ void fma4(const float4 a, const float4 b, float& d) {
  d = fmaf(a.x, b.x, d); d = fmaf(a.y, b.y, d);
  d = fmaf(a.z, b.z, d); d = fmaf(a.w, b.w, d);
}

__global__ __launch_bounds__(256)
void evid_fused(const float* __restrict__ X, const float* __restrict__ Wm,
                const float* __restrict__ BETA, const float* __restrict__ ALPHA,
                const float* __restrict__ GAMMA, float* __restrict__ OUT)
{
  __shared__ __align__(16) float xs[DSL][LDX], wsh[DSL][LDX], ssf[TKF][LDX], vs[OC][LDX];
  __shared__ float xq[TBF], wq[TKF], apch[TKF], g2ch[TKF];
  __shared__ float redx[4][TBF], redw[4][TKF];
  const int t = threadIdx.x, bbase = blockIdx.x * TBF;
  const int tb = t & 15, tk = t >> 4, srow = t >> 4, sdq = t & 15;
  const int cbf = t & 63, part = t >> 6;
  float Ap[OC];
  #pragma unroll
  for (int c = 0; c < OC; ++c) Ap[c] = 1.0f;
  float xqacc = 0.0f;
  for (int chunk = 0; chunk < 8; ++chunk) {
    const int k0 = chunk * TKF;
    __syncthreads();
    if (t < TKF) {
      const int k = k0 + t;
      float bsum = 0.0f;
      #pragma unroll
      for (int c = 0; c < NCLS; ++c) { const float bv = BETA[k*NCLS+c]; bsum = fmaf(bv, bv, bsum); }
      const float binv = 1.0f / bsum;
      #pragma unroll
      for (int c = 0; c < NCLS; ++c) { const float bv = BETA[k*NCLS+c]; vs[c][t] = 1.0f - bv*bv*binv; }
      vs[NCLS][t] = 1.0f;
      apch[t] = 0.99f / (1.0f + expf(-ALPHA[k]));
      const float gv = GAMMA[k]; g2ch[t] = gv * gv;
    }
    float acc[4][4] = {};
    float wqacc = 0.0f;
    for (int sl = 0; sl < 4; ++sl) {
      const int d0 = sl * DSL;
      __syncthreads();
      #pragma unroll
      for (int p = 0; p < 4; ++p) {
        const int r = srow + 16 * p;
        *(float4*)&xs [r][4*sdq] = *(const float4*)&X [(size_t)(bbase + r)*ND + d0 + 4*sdq];
        *(float4*)&wsh[r][4*sdq] = *(const float4*)&Wm[(size_t)(k0    + r)*ND + d0 + 4*sdq];
      }
      __syncthreads();
      #pragma unroll
      for (int m = 0; m < 4; ++m) {
        const float4 v = *(const float4*)&wsh[cbf][part*16 + 4*m];
        wqacc = fmaf(v.x,v.x, fmaf(v.y,v.y, fmaf(v.z,v.z, fmaf(v.w,v.w, wqacc))));
      }
      if (chunk == 0) {
        #pragma unroll
        for (int m = 0; m < 4; ++m) {
          const float4 v = *(const float4*)&xs[cbf][part*16 + 4*m];
          xqacc = fmaf(v.x,v.x, fmaf(v.y,v.y, fmaf(v.z,v.z, fmaf(v.w,v.w, xqacc))));
        }
      }
      #pragma unroll
      for (int dq = 0; dq < 16; ++dq) {
        const float4 xa0 = *(const float4*)&xs [tb +  0][4*dq];
        const float4 xa1 = *(const float4*)&xs [tb + 16][4*dq];
        const float4 xa2 = *(const float4*)&xs [tb + 32][4*dq];
        const float4 xa3 = *(const float4*)&xs [tb + 48][4*dq];
        const float4 wb0 = *(const float4*)&wsh[tk +  0][4*dq];
        const float4 wb1 = *(const float4*)&wsh[tk + 16][4*dq];
        const float4 wb2 = *(const float4*)&wsh[tk + 32][4*dq];
        const float4 wb3 = *(const float4*)&wsh[tk + 48][4*dq];
        fma4(xa0, wb0, acc[0][0]); fma4(xa0, wb1, acc[0][1]); fma4(xa0, wb2, acc[0][2]); fma4(xa0, wb3, acc[0][3]);
        fma4(xa1, wb0, acc[1][0]); fma4(xa1, wb1, acc[1][1]); fma4(xa1, wb2, acc[1][2]); fma4(xa1, wb3, acc[1][3]);
        fma4(xa2, wb0, acc[2][0]); fma4(xa2, wb1, acc[2][1]); fma4(xa2, wb2, acc[2][2]); fma4(xa2, wb3, acc[2][3]);
        fma4(xa3, wb0, acc[3][0]); fma4(xa3, wb1, acc[3][1]); fma4(xa3, wb2, acc[3][2]); fma4(xa3, wb3, acc[3][3]);
      }
    }
    redw[part][cbf] = wqacc;
    if (chunk == 0) redx[part][cbf] = xqacc;
    __syncthreads();
    if (t < TKF) {
      wq[t] = redw[0][t] + redw[1][t] + redw[2][t] + redw[3][t];
      if (chunk == 0) xq[t] = redx[0][t] + redx[1][t] + redx[2][t] + redx[3][t];
    }
    __syncthreads();
    #pragma unroll
    for (int j = 0; j < 4; ++j) {
      const int kj = tk + 16 * j;
      const float wqk = wq[kj], ap = apch[kj], g2 = g2ch[kj];
      #pragma unroll
      for (int i = 0; i < 4; ++i) {
        const int bi = tb + 16 * i;
        ssf[kj][bi] = ap * expf(-g2 * (0.5f*(wqk + xq[bi]) - acc[i][j]));
      }
    }
    __syncthreads();
    {
      float sv[16];
      #pragma unroll
      for (int m = 0; m < 16; ++m) sv[m] = ssf[16*part + m][cbf];
      #pragma unroll
      for (int c = 0; c < OC; ++c) {
        float a = Ap[c];
        #pragma unroll
        for (int mq = 0; mq < 4; ++mq) {
          const float4 vv = *(const float4*)&vs[c][16*part + 4*mq];
          const float t0 = fmaf(-sv[4*mq+0], vv.x, 1.0f);
          const float t1 = fmaf(-sv[4*mq+1], vv.y, 1.0f);
          const float t2 = fmaf(-sv[4*mq+2], vv.z, 1.0f);
          const float t3 = fmaf(-sv[4*mq+3], vv.w, 1.0f);
          a = a * ((t0*t1)*(t2*t3));
        }
        Ap[c] = a;
      }
    }
  }
  __syncthreads();
  if (part >= 2) {
    #pragma unroll
    for (int c = 0; c < OC; ++c) ssf[(part-2)*OC + c][cbf] = Ap[c];
  }
  __syncthreads();
  if (part < 2) {
    #pragma unroll
    for (int c = 0; c < OC; ++c) Ap[c] *= ssf[part*OC + c][cbf];
  }
  __syncthreads();
  if (part == 1) {
    #pragma unroll
    for (int c = 0; c < OC; ++c) ssf[c][cbf] = Ap[c];
  }
  __syncthreads();
  if (part == 0) {
    #pragma unroll
    for (int c = 0; c < OC; ++c) Ap[c] *= ssf[c][cbf];
    const float Nv = Ap[NCLS];
    float Ks = Nv;
    #pragma unroll
    for (int c = 0; c < NCLS; ++c) Ks += Ap[c] - Nv;
    const float invk = 1.0f / Ks;
    #pragma unroll
    for (int c = 0; c < NCLS; ++c) ssf[c][cbf] = (Ap[c] - Nv) * invk;
    ssf[NCLS][cbf] = Nv * invk;
  }
  __syncthreads();
  for (int idx = t; idx < TBF*OC; idx += 256) {
    const int b = idx / OC, c = idx - b*OC;
    OUT[(size_t)bbase*OC + idx] = ssf[c][b];
  }
}

extern "C" void kernel_launch(void* const* d_in, const int* in_sizes, int n_in,
                              void* d_out, int out_size, void* d_ws, size_t ws_size,
                              hipStream_t stream) {
  (void)in_sizes; (void)n_in; (void)out_size;
  const float* X     = (const float*)d_in[0];
  const float* Wm    = (const float*)d_in[1];
  const float* BETA  = (const float*)d_in[2];
  const float* ALPHA = (const float*)d_in[3];
  const float* GAMMA = (const float*)d_in[4];
  float* OUT = (float*)d_out;

  if (ws_size < WS_NEED) {   // fallback: verified f32 path
    hipLaunchKernelGGL(evid_fused, dim3(NBATCH/TBF), dim3(256), 0, stream,
                       X, Wm, BETA, ALPHA, GAMMA, OUT);
    return;
  }
  char* ws = (char*)d_ws;
  unsigned short* PXH = (unsigned short*)(ws + OFF_PXH);
  unsigned short* PXL = (unsigned short*)(ws + OFF_PXL);
  unsigned short* PWH = (unsigned short*)(ws + OFF_PWH);
  unsigned short* PWL = (unsigned short*)(ws + OFF_PWL);
  float* XQ  = (float*)(ws + OFF_XQ);
  float* WQ  = (float*)(ws + OFF_WQ);
  float* APH = (float*)(ws + OFF_APH);
  float* G2A = (float*)(ws + OFF_G2A);

  hipLaunchKernelGGL(convert_pack, dim3(NBATCH*32/256), dim3(256), 0, stream,
                     X, PXH, PXL, XQ, NBATCH);
  hipLaunchKernelGGL(convert_pack, dim3(NP*32/256), dim3(256), 0, stream,
                     Wm, PWH, PWL, WQ, NP);
  hipLaunchKernelGGL(prep_scalars, dim3(2), dim3(256), 0, stream,
                     ALPHA, GAMMA, APH, G2A);
  hipLaunchKernelGGL(evid_mfma, dim3(NBATCH/32), dim3(256), 0, stream,
                     PXH, PXL, PWH, PWL, XQ, WQ, APH, G2A, BETA, OUT);
}

// Round 5
// 166.994 us; speedup vs baseline: 1.2155x; 1.0112x over previous
//
#include <hip/hip_runtime.h>
#include <math.h>

// EvidNets fused, MFMA bf16x2, single-pass X conversion.
//   A_c(b) = prod_k (1 - s_kb * (1 - U_kc)),  N(b) = prod_k (1 - s_kb)
//   out[b][c<20] = (A_c - N)/K,  out[b][20] = N/K,  K = sum_c A_c - 19*N
//   s_kb = alphap_k * exp(-gamma_k^2 * (0.5*(|W_k|^2 + |x_b|^2) - W_k.x_b))
// GEMM W@X^T via v_mfma_f32_32x32x16_bf16 on hi/lo bf16 split (3 MFMAs/step).
// X is converted to fragment layout in-kernel (no X pre-pass); W (tiny) is
// pre-packed into d_ws; 1-U / alphap / gamma^2 precomputed into d_ws.

#define NBATCH 16384
#define ND     256
#define NP     512
#define NCLS   20
#define OC     21

typedef short  short8  __attribute__((ext_vector_type(8)));
typedef short  short4v __attribute__((ext_vector_type(4)));
typedef unsigned short ushort8 __attribute__((ext_vector_type(8)));
typedef float  f32x16  __attribute__((ext_vector_type(16)));

// ---- workspace layout (bytes) ----
#define OFF_PWH 0u
#define OFF_PWL 262144u
#define OFF_VS  524288u                 // float VS[21][512] = 1-U (row 20 = 1)
#define OFF_WQ  (OFF_VS + 43008u)
#define OFF_AP  (OFF_WQ + 2048u)
#define OFF_G2  (OFF_AP + 2048u)
#define WS_NEED ((size_t)(OFF_G2 + 2048u))

__device__ __forceinline__ unsigned short f2bf_rn(float f) {
  unsigned int u = __float_as_uint(f);
  unsigned int r = (u + 0x7FFFu + ((u >> 16) & 1u)) >> 16;   // RNE (finite inputs)
  return (unsigned short)r;
}
__device__ __forceinline__ float bf2f(unsigned short h) {
  return __uint_as_float(((unsigned int)h) << 16);
}

// Pack W[512][256] f32 -> MFMA B-fragment order hi/lo bf16 + row sum-squares.
// frag elem (tile,step,lane,j) = src[tile*32+(lane&31)][step*16+8*(lane>>5)+j]
__global__ __launch_bounds__(256)
void pack_w(const float* __restrict__ src, unsigned short* __restrict__ dh,
            unsigned short* __restrict__ dl, float* __restrict__ sq)
{
  const int tid = blockIdx.x * 256 + threadIdx.x;
  const int row = tid >> 5, seg = tid & 31;
  if (row >= NP) return;
  const float4* s4 = (const float4*)(src + (size_t)row * ND + seg * 8);
  const float4 a = s4[0], b = s4[1];
  const float v[8] = {a.x, a.y, a.z, a.w, b.x, b.y, b.z, b.w};
  ushort8 hv, lv;
  float ssq = 0.f;
  #pragma unroll
  for (int j = 0; j < 8; ++j) {
    ssq = fmaf(v[j], v[j], ssq);
    const unsigned short hh = f2bf_rn(v[j]);
    hv[j] = hh;
    lv[j] = f2bf_rn(v[j] - bf2f(hh));
  }
  const int tile = row >> 5, m = row & 31, step = seg >> 1, r = seg & 1;
  const size_t cidx = (size_t)(tile * 16 + step) * 64 + m + 32 * r;
  *(ushort8*)(dh + cidx * 8) = hv;
  *(ushort8*)(dl + cidx * 8) = lv;
  #pragma unroll
  for (int off = 1; off < 32; off <<= 1) ssq += __shfl_xor(ssq, off, 64);
  if (seg == 0) sq[row] = ssq;
}

// Per-prototype tables: VS[c][k] = 1 - U[k][c] (VS[20][k]=1), alphap, gamma^2.
__global__ __launch_bounds__(256)
void prep_scalars(const float* __restrict__ BETA, const float* __restrict__ alpha,
                  const float* __restrict__ gamma, float* __restrict__ VS,
                  float* __restrict__ AP, float* __restrict__ G2)
{
  const int k = blockIdx.x * 256 + threadIdx.x;
  if (k >= NP) return;
  float bv[NCLS], bs = 0.f;
  #pragma unroll
  for (int c = 0; c < NCLS; ++c) { bv[c] = BETA[k * NCLS + c]; bs = fmaf(bv[c], bv[c], bs); }
  const float binv = 1.f / bs;
  #pragma unroll
  for (int c = 0; c < NCLS; ++c) VS[c * NP + k] = 1.f - bv[c] * bv[c] * binv;
  VS[NCLS * NP + k] = 1.f;
  AP[k] = 0.99f / (1.f + __expf(-alpha[k]));
  const float g = gamma[k];
  G2[k] = g * g;
}

// Main kernel: 512 blocks x 256 threads, 32 samples/block. Wave w owns the
// 32x32 (sample x proto) tile for protos [chunk*128 + w*32, +32), 4 chunks.
__global__ __launch_bounds__(256, 2)
void evid_main(const float* __restrict__ X,
               const unsigned short* __restrict__ PWH, const unsigned short* __restrict__ PWL,
               const float* __restrict__ VS, const float* __restrict__ WQ,
               const float* __restrict__ AP, const float* __restrict__ G2,
               float* __restrict__ OUT)
{
  __shared__ __align__(16) short Ah[8192], Al[8192];  // A-frags: (step*64+lane)*8
  __shared__ float ss[128 * 33];          // s[p_local][b], stride 33
  __shared__ float vsd[OC * 128];         // vsd[c][k_local]
  __shared__ float xqs[32], wqs[128], aps[128], g2s[128];
  __shared__ float redq[32][8];

  const int t    = threadIdx.x;
  const int lane = t & 63, wave = t >> 6;
  const int tile = blockIdx.x;
  const int bbase = tile * 32;

  // ---- stage: convert X rows f32 -> hi/lo bf16 fragments in LDS ----
  {
    const int r  = t >> 3;                // sample row 0..31
    const int sg = t & 7;                 // float4 slot within 32-col group
    const float* xrow = X + (size_t)(bbase + r) * ND;
    float ssq = 0.f;
    #pragma unroll
    for (int it = 0; it < 8; ++it) {
      const int c0 = it * 32 + sg * 4;
      const float4 v = *(const float4*)(xrow + c0);
      const float vv[4] = {v.x, v.y, v.z, v.w};
      short4v h4, l4;
      #pragma unroll
      for (int j = 0; j < 4; ++j) {
        ssq = fmaf(vv[j], vv[j], ssq);
        const unsigned short hh = f2bf_rn(vv[j]);
        h4[j] = (short)hh;
        l4[j] = (short)f2bf_rn(vv[j] - bf2f(hh));
      }
      const int step = c0 >> 4, half = (c0 >> 3) & 1, j0 = c0 & 7;
      const int base = (step * 64 + (r + 32 * half)) * 8 + j0;
      *(short4v*)&Ah[base] = h4;
      *(short4v*)&Al[base] = l4;
    }
    redq[r][sg] = ssq;
  }
  __syncthreads();
  if (t < 32) {
    float s = 0.f;
    #pragma unroll
    for (int j = 0; j < 8; ++j) s += redq[t][j];
    xqs[t] = s;
  }

  float Ap[OC];
  #pragma unroll
  for (int c = 0; c < OC; ++c) Ap[c] = 1.0f;

  #pragma unroll 1
  for (int chunk = 0; chunk < 4; ++chunk) {
    __syncthreads();   // prev combine's reads of ss/vsd done; stage visible

    for (int i = t; i < OC * 128; i += 256)      // vsd[c][kk] <- VS table
      vsd[i] = VS[(i >> 7) * NP + chunk * 128 + (i & 127)];
    if (t < 128) {
      const int k = chunk * 128 + t;
      wqs[t] = WQ[k]; aps[t] = AP[k]; g2s[t] = G2[k];
    }

    // MFMA: 32x32 tile over K=256, hi/lo 3-pass
    f32x16 acc;
    #pragma unroll
    for (int i = 0; i < 16; ++i) acc[i] = 0.f;
    const int ptile = chunk * 4 + wave;
    const short8* bH = (const short8*)PWH + (size_t)ptile * 16 * 64 + lane;
    const short8* bL = (const short8*)PWL + (size_t)ptile * 16 * 64 + lane;
    const short8* aH = (const short8*)Ah + lane;
    const short8* aL = (const short8*)Al + lane;
    #pragma unroll
    for (int step = 0; step < 16; ++step) {
      const short8 ah = aH[step * 64], al = aL[step * 64];
      const short8 bh = bH[step * 64], bl = bL[step * 64];
      acc = __builtin_amdgcn_mfma_f32_32x32x16_bf16(ah, bh, acc, 0, 0, 0);
      acc = __builtin_amdgcn_mfma_f32_32x32x16_bf16(ah, bl, acc, 0, 0, 0);
      acc = __builtin_amdgcn_mfma_f32_32x32x16_bf16(al, bh, acc, 0, 0, 0);
    }
    __syncthreads();   // vsd/params visible

    // epilogue: s = alphap * exp(-g2 * (0.5*(wq+xq) - dot))
    // C/D layout: col(n)=lane&31, row(m)=(reg&3)+8*(reg>>2)+4*(lane>>5)
    {
      const int   pl  = wave * 32 + (lane & 31);
      const float wqk = wqs[pl], apk = aps[pl], g2k = g2s[pl];
      const int   rb  = 4 * (lane >> 5);
      #pragma unroll
      for (int rg = 0; rg < 16; ++rg) {
        const int   m  = (rg & 3) + 8 * (rg >> 2) + rb;
        const float dv = 0.5f * (wqk + xqs[m]) - acc[rg];
        ss[pl * 33 + m] = apk * __expf(-g2k * dv);
      }
    }
    __syncthreads();   // ss ready

    // combine: thread (cb=t&31, part=t>>5) folds its 16 k's into Ap[21]
    {
      const int cb = t & 31, part = t >> 5;
      float sv[16];
      #pragma unroll
      for (int i = 0; i < 16; ++i) sv[i] = ss[(part * 16 + i) * 33 + cb];
      #pragma unroll
      for (int c = 0; c < OC; ++c) {
        const float* vc = &vsd[c * 128 + part * 16];
        float a = Ap[c];
        #pragma unroll
        for (int q = 0; q < 4; ++q) {
          const float t0 = fmaf(-sv[4*q+0], vc[4*q+0], 1.0f);
          const float t1 = fmaf(-sv[4*q+1], vc[4*q+1], 1.0f);
          const float t2 = fmaf(-sv[4*q+2], vc[4*q+2], 1.0f);
          const float t3 = fmaf(-sv[4*q+3], vc[4*q+3], 1.0f);
          a = a * ((t0 * t1) * (t2 * t3));
        }
        Ap[c] = a;
      }
    }
  }

  // cross-part product reduction (8 partials per (b,c)), normalize, store
  const int cb = t & 31, part = t >> 5;
  __syncthreads();
  if (part >= 4) {
    #pragma unroll
    for (int c = 0; c < OC; ++c) ss[((part - 4) * OC + c) * 33 + cb] = Ap[c];
  }
  __syncthreads();
  if (part < 4) {
    #pragma unroll
    for (int c = 0; c < OC; ++c) Ap[c] *= ss[(part * OC + c) * 33 + cb];
  }
  __syncthreads();
  if (part >= 2 && part < 4) {
    #pragma unroll
    for (int c = 0; c < OC; ++c) ss[((part - 2) * OC + c) * 33 + cb] = Ap[c];
  }
  __syncthreads();
  if (part < 2) {
    #pragma unroll
    for (int c = 0; c < OC; ++c) Ap[c] *= ss[(part * OC + c) * 33 + cb];
  }
  __syncthreads();
  if (part == 1) {
    #pragma unroll
    for (int c = 0; c < OC; ++c) ss[c * 33 + cb] = Ap[c];
  }
  __syncthreads();
  if (part == 0) {
    #pragma unroll
    for (int c = 0; c < OC; ++c) Ap[c] *= ss[c * 33 + cb];
    const float Nv = Ap[NCLS];
    float Ks = Nv;
    #pragma unroll
    for (int c = 0; c < NCLS; ++c) Ks += Ap[c] - Nv;
    const float invk = 1.0f / Ks;
    #pragma unroll
    for (int c = 0; c < NCLS; ++c) ss[c * 33 + cb] = (Ap[c] - Nv) * invk;
    ss[NCLS * 33 + cb] = Nv * invk;
  }
  __syncthreads();
  for (int idx = t; idx < 32 * OC; idx += 256) {
    const int b = idx / OC, c = idx - b * OC;
    OUT[(size_t)tile * 32 * OC + idx] = ss[c * 33 + b];
  }
}

// ---------------- fallback (verified f32 path, used if ws too small) ----------------
#define TBF 64
#define TKF 64
#define DSL 64
#define LDX 68

__device__ __forceinline__ void fma4(const float4 a, const float4 b, float& d) {
  d = fmaf(a.x, b.x, d); d = fmaf(a.y, b.y, d);
  d = fmaf(a.z, b.z, d); d = fmaf(a.w, b.w, d);
}

__global__ __launch_bounds__(256)
void evid_fused(const float* __restrict__ X, const float* __restrict__ Wm,
                const float* __restrict__ BETA, const float* __restrict__ ALPHA,
                const float* __restrict__ GAMMA, float* __restrict__ OUT)
{
  __shared__ __align__(16) float xs[DSL][LDX], wsh[DSL][LDX], ssf[TKF][LDX], vs[OC][LDX];
  __shared__ float xq[TBF], wq[TKF], apch[TKF], g2ch[TKF];
  __shared__ float redx[4][TBF], redw[4][TKF];
  const int t = threadIdx.x, bbase = blockIdx.x * TBF;
  const int tb = t & 15, tk = t >> 4, srow = t >> 4, sdq = t & 15;
  const int cbf = t & 63, part = t >> 6;
  float Ap[OC];
  #pragma unroll
  for (int c = 0; c < OC; ++c) Ap[c] = 1.0f;
  float xqacc = 0.0f;
  for (int chunk = 0; chunk < 8; ++chunk) {
    const int k0 = chunk * TKF;
    __syncthreads();
    if (t < TKF) {
      const int k = k0 + t;
      float bsum = 0.0f;
      #pragma unroll
      for (int c = 0; c < NCLS; ++c) { const float bv = BETA[k*NCLS+c]; bsum = fmaf(bv, bv, bsum); }
      const float binv = 1.0f / bsum;
      #pragma unroll
      for (int c = 0; c < NCLS; ++c) { const float bv = BETA[k*NCLS+c]; vs[c][t] = 1.0f - bv*bv*binv; }
      vs[NCLS][t] = 1.0f;
      apch[t] = 0.99f / (1.0f + expf(-ALPHA[k]));
      const float gv = GAMMA[k]; g2ch[t] = gv * gv;
    }
    float acc[4][4] = {};
    float wqacc = 0.0f;
    for (int sl = 0; sl < 4; ++sl) {
      const int d0 = sl * DSL;
      __syncthreads();
      #pragma unroll
      for (int p = 0; p < 4; ++p) {
        const int r = srow + 16 * p;
        *(float4*)&xs [r][4*sdq] = *(const float4*)&X [(size_t)(bbase + r)*ND + d0 + 4*sdq];
        *(float4*)&wsh[r][4*sdq] = *(const float4*)&Wm[(size_t)(k0    + r)*ND + d0 + 4*sdq];
      }
      __syncthreads();
      #pragma unroll
      for (int m = 0; m < 4; ++m) {
        const float4 v = *(const float4*)&wsh[cbf][part*16 + 4*m];
        wqacc = fmaf(v.x,v.x, fmaf(v.y,v.y, fmaf(v.z,v.z, fmaf(v.w,v.w, wqacc))));
      }
      if (chunk == 0) {
        #pragma unroll
        for (int m = 0; m < 4; ++m) {
          const float4 v = *(const float4*)&xs[cbf][part*16 + 4*m];
          xqacc = fmaf(v.x,v.x, fmaf(v.y,v.y, fmaf(v.z,v.z, fmaf(v.w,v.w, xqacc))));
        }
      }
      #pragma unroll
      for (int dq = 0; dq < 16; ++dq) {
        const float4 xa0 = *(const float4*)&xs [tb +  0][4*dq];
        const float4 xa1 = *(const float4*)&xs [tb + 16][4*dq];
        const float4 xa2 = *(const float4*)&xs [tb + 32][4*dq];
        const float4 xa3 = *(const float4*)&xs [tb + 48][4*dq];
        const float4 wb0 = *(const float4*)&wsh[tk +  0][4*dq];
        const float4 wb1 = *(const float4*)&wsh[tk + 16][4*dq];
        const float4 wb2 = *(const float4*)&wsh[tk + 32][4*dq];
        const float4 wb3 = *(const float4*)&wsh[tk + 48][4*dq];
        fma4(xa0, wb0, acc[0][0]); fma4(xa0, wb1, acc[0][1]); fma4(xa0, wb2, acc[0][2]); fma4(xa0, wb3, acc[0][3]);
        fma4(xa1, wb0, acc[1][0]); fma4(xa1, wb1, acc[1][1]); fma4(xa1, wb2, acc[1][2]); fma4(xa1, wb3, acc[1][3]);
        fma4(xa2, wb0, acc[2][0]); fma4(xa2, wb1, acc[2][1]); fma4(xa2, wb2, acc[2][2]); fma4(xa2, wb3, acc[2][3]);
        fma4(xa3, wb0, acc[3][0]); fma4(xa3, wb1, acc[3][1]); fma4(xa3, wb2, acc[3][2]); fma4(xa3, wb3, acc[3][3]);
      }
    }
    redw[part][cbf] = wqacc;
    if (chunk == 0) redx[part][cbf] = xqacc;
    __syncthreads();
    if (t < TKF) {
      wq[t] = redw[0][t] + redw[1][t] + redw[2][t] + redw[3][t];
      if (chunk == 0) xq[t] = redx[0][t] + redx[1][t] + redx[2][t] + redx[3][t];
    }
    __syncthreads();
    #pragma unroll
    for (int j = 0; j < 4; ++j) {
      const int kj = tk + 16 * j;
      const float wqk = wq[kj], ap = apch[kj], g2 = g2ch[kj];
      #pragma unroll
      for (int i = 0; i < 4; ++i) {
        const int bi = tb + 16 * i;
        ssf[kj][bi] = ap * expf(-g2 * (0.5f*(wqk + xq[bi]) - acc[i][j]));
      }
    }
    __syncthreads();
    {
      float sv[16];
      #pragma unroll
      for (int m = 0; m < 16; ++m) sv[m] = ssf[16*part + m][cbf];
      #pragma unroll
      for (int c = 0; c < OC; ++c) {
        float a = Ap[c];
        #pragma unroll
        for (int mq = 0; mq < 4; ++mq) {
          const float4 vv = *(const float4*)&vs[c][16*part + 4*mq];
          const float t0 = fmaf(-sv[4*mq+0], vv.x, 1.0f);
          const float t1 = fmaf(-sv[4*mq+1], vv.y, 1.0f);
          const float t2 = fmaf(-sv[4*mq+2], vv.z, 1.0f);
          const float t3 = fmaf(-sv[4*mq+3], vv.w, 1.0f);
          a = a * ((t0*t1)*(t2*t3));
        }
        Ap[c] = a;
      }
    }
  }
  __syncthreads();
  if (part >= 2) {
    #pragma unroll
    for (int c = 0; c < OC; ++c) ssf[(part-2)*OC + c][cbf] = Ap[c];
  }
  __syncthreads();
  if (part < 2) {
    #pragma unroll
    for (int c = 0; c < OC; ++c) Ap[c] *= ssf[part*OC + c][cbf];
  }
  __syncthreads();
  if (part == 1) {
    #pragma unroll
    for (int c = 0; c < OC; ++c) ssf[c][cbf] = Ap[c];
  }
  __syncthreads();
  if (part == 0) {
    #pragma unroll
    for (int c = 0; c < OC; ++c) Ap[c] *= ssf[c][cbf];
    const float Nv = Ap[NCLS];
    float Ks = Nv;
    #pragma unroll
    for (int c = 0; c < NCLS; ++c) Ks += Ap[c] - Nv;
    const float invk = 1.0f / Ks;
    #pragma unroll
    for (int c = 0; c < NCLS; ++c) ssf[c][cbf] = (Ap[c] - Nv) * invk;
    ssf[NCLS][cbf] = Nv * invk;
  }
  __syncthreads();
  for (int idx = t; idx < TBF*OC; idx += 256) {
    const int b = idx / OC, c = idx - b*OC;
    OUT[(size_t)bbase*OC + idx] = ssf[c][b];
  }
}

extern "C" void kernel_launch(void* const* d_in, const int* in_sizes, int n_in,
                              void* d_out, int out_size, void* d_ws, size_t ws_size,
                              hipStream_t stream) {
  (void)in_sizes; (void)n_in; (void)out_size;
  const float* X     = (const float*)d_in[0];
  const float* Wm    = (const float*)d_in[1];
  const float* BETA  = (const float*)d_in[2];
  const float* ALPHA = (const float*)d_in[3];
  const float* GAMMA = (const float*)d_in[4];
  float* OUT = (float*)d_out;

  if (ws_size < WS_NEED) {   // fallback: verified f32 path
    hipLaunchKernelGGL(evid_fused, dim3(NBATCH/TBF), dim3(256), 0, stream,
                       X, Wm, BETA, ALPHA, GAMMA, OUT);
    return;
  }
  char* ws = (char*)d_ws;
  unsigned short* PWH = (unsigned short*)(ws + OFF_PWH);
  unsigned short* PWL = (unsigned short*)(ws + OFF_PWL);
  float* VS = (float*)(ws + OFF_VS);
  float* WQ = (float*)(ws + OFF_WQ);
  float* AP = (float*)(ws + OFF_AP);
  float* G2 = (float*)(ws + OFF_G2);

  hipLaunchKernelGGL(pack_w, dim3(NP*32/256), dim3(256), 0, stream, Wm, PWH, PWL, WQ);
  hipLaunchKernelGGL(prep_scalars, dim3(2), dim3(256), 0, stream, BETA, ALPHA, GAMMA, VS, AP, G2);
  hipLaunchKernelGGL(evid_main, dim3(NBATCH/32), dim3(256), 0, stream,
                     X, PWH, PWL, VS, WQ, AP, G2, OUT);
}

// Round 6
// 129.612 us; speedup vs baseline: 1.5660x; 1.2884x over previous
//
#include <hip/hip_runtime.h>
#include <math.h>

// EvidNets fused, MFMA bf16x2, single-pass X conversion.
//   A_c(b) = prod_k (1 - s_kb * (1 - U_kc)),  N(b) = prod_k (1 - s_kb)
//   out[b][c<20] = (A_c - N)/K,  out[b][20] = N/K,  K = sum_c A_c - 19*N
//   s_kb = alphap_k * exp(-gamma_k^2 * (0.5*(|W_k|^2 + |x_b|^2) - W_k.x_b))
// GEMM W@X^T via v_mfma_f32_32x32x16_bf16 on hi/lo bf16 split (3 MFMAs/step).
// NOTE: __launch_bounds__(256) WITHOUT a min-waves arg — (256,2) made the
// allocator cap arch-VGPRs at 128 and spill ~260B/thread to scratch
// (R4/R5: WRITE_SIZE 136-145 MB, all pipes idle). LDS caps us at 2 blocks/CU
// anyway, so extra occupancy pressure is pure loss.

#define NBATCH 16384
#define ND     256
#define NP     512
#define NCLS   20
#define OC     21

typedef short  short8  __attribute__((ext_vector_type(8)));
typedef short  short4v __attribute__((ext_vector_type(4)));
typedef unsigned short ushort8 __attribute__((ext_vector_type(8)));
typedef float  f32x16  __attribute__((ext_vector_type(16)));

// ---- workspace layout (bytes) ----
#define OFF_PWH 0u
#define OFF_PWL 262144u
#define OFF_VS  524288u                 // float VS[21][512] = 1-U (row 20 = 1)
#define OFF_WQ  (OFF_VS + 43008u)
#define OFF_AP  (OFF_WQ + 2048u)
#define OFF_G2  (OFF_AP + 2048u)
#define WS_NEED ((size_t)(OFF_G2 + 2048u))

__device__ __forceinline__ unsigned short f2bf_rn(float f) {
  unsigned int u = __float_as_uint(f);
  unsigned int r = (u + 0x7FFFu + ((u >> 16) & 1u)) >> 16;   // RNE (finite inputs)
  return (unsigned short)r;
}
__device__ __forceinline__ float bf2f(unsigned short h) {
  return __uint_as_float(((unsigned int)h) << 16);
}

// Combined prep: blocks 0..63 pack W[512][256] -> MFMA B-fragment order hi/lo
// bf16 + row sum-squares; blocks 64..65 build VS/AP/G2 tables.
// frag elem (tile,step,lane,j) = src[tile*32+(lane&31)][step*16+8*(lane>>5)+j]
__global__ __launch_bounds__(256)
void prep(const float* __restrict__ Wsrc, const float* __restrict__ BETA,
          const float* __restrict__ alpha, const float* __restrict__ gamma,
          unsigned short* __restrict__ dh, unsigned short* __restrict__ dl,
          float* __restrict__ sq, float* __restrict__ VS,
          float* __restrict__ AP, float* __restrict__ G2)
{
  const int bid = blockIdx.x;
  if (bid < 64) {                      // ---- pack W ----
    const int tid = bid * 256 + threadIdx.x;
    const int row = tid >> 5, seg = tid & 31;
    const float4* s4 = (const float4*)(Wsrc + (size_t)row * ND + seg * 8);
    const float4 a = s4[0], b = s4[1];
    const float v[8] = {a.x, a.y, a.z, a.w, b.x, b.y, b.z, b.w};
    ushort8 hv, lv;
    float ssq = 0.f;
    #pragma unroll
    for (int j = 0; j < 8; ++j) {
      ssq = fmaf(v[j], v[j], ssq);
      const unsigned short hh = f2bf_rn(v[j]);
      hv[j] = hh;
      lv[j] = f2bf_rn(v[j] - bf2f(hh));
    }
    const int tile = row >> 5, m = row & 31, step = seg >> 1, r = seg & 1;
    const size_t cidx = (size_t)(tile * 16 + step) * 64 + m + 32 * r;
    *(ushort8*)(dh + cidx * 8) = hv;
    *(ushort8*)(dl + cidx * 8) = lv;
    #pragma unroll
    for (int off = 1; off < 32; off <<= 1) ssq += __shfl_xor(ssq, off, 64);
    if (seg == 0) sq[row] = ssq;
  } else {                             // ---- scalar tables ----
    const int k = (bid - 64) * 256 + threadIdx.x;
    if (k >= NP) return;
    float bv[NCLS], bs = 0.f;
    #pragma unroll
    for (int c = 0; c < NCLS; ++c) { bv[c] = BETA[k * NCLS + c]; bs = fmaf(bv[c], bv[c], bs); }
    const float binv = 1.f / bs;
    #pragma unroll
    for (int c = 0; c < NCLS; ++c) VS[c * NP + k] = 1.f - bv[c] * bv[c] * binv;
    VS[NCLS * NP + k] = 1.f;
    AP[k] = 0.99f / (1.f + __expf(-alpha[k]));
    const float g = gamma[k];
    G2[k] = g * g;
  }
}

// Main kernel: 512 blocks x 256 threads, 32 samples/block. Wave w owns the
// 32x32 (sample x proto) tile for protos [chunk*128 + w*32, +32), 4 chunks.
__global__ __launch_bounds__(256)
void evid_main(const float* __restrict__ X,
               const unsigned short* __restrict__ PWH, const unsigned short* __restrict__ PWL,
               const float* __restrict__ VS, const float* __restrict__ WQ,
               const float* __restrict__ AP, const float* __restrict__ G2,
               float* __restrict__ OUT)
{
  __shared__ __align__(16) short Ah[8192], Al[8192];  // A-frags: (step*64+lane)*8
  __shared__ float ss[128 * 33];          // s[p_local][b], stride 33
  __shared__ float vsd[OC * 128];         // vsd[c][k_local]
  __shared__ float xqs[32], wqs[128], aps[128], g2s[128];
  __shared__ float redq[32][8];

  const int t    = threadIdx.x;
  const int lane = t & 63, wave = t >> 6;
  const int tile = blockIdx.x;
  const int bbase = tile * 32;

  // ---- stage: convert X rows f32 -> hi/lo bf16 fragments in LDS ----
  {
    const int r  = t >> 3;                // sample row 0..31
    const int sg = t & 7;                 // float4 slot within 32-col group
    const float* xrow = X + (size_t)(bbase + r) * ND;
    float ssq = 0.f;
    #pragma unroll
    for (int it = 0; it < 8; ++it) {
      const int c0 = it * 32 + sg * 4;
      const float4 v = *(const float4*)(xrow + c0);
      const float vv[4] = {v.x, v.y, v.z, v.w};
      short4v h4, l4;
      #pragma unroll
      for (int j = 0; j < 4; ++j) {
        ssq = fmaf(vv[j], vv[j], ssq);
        const unsigned short hh = f2bf_rn(vv[j]);
        h4[j] = (short)hh;
        l4[j] = (short)f2bf_rn(vv[j] - bf2f(hh));
      }
      const int step = c0 >> 4, half = (c0 >> 3) & 1, j0 = c0 & 7;
      const int base = (step * 64 + (r + 32 * half)) * 8 + j0;
      *(short4v*)&Ah[base] = h4;
      *(short4v*)&Al[base] = l4;
    }
    redq[r][sg] = ssq;
  }
  __syncthreads();
  if (t < 32) {
    float s = 0.f;
    #pragma unroll
    for (int j = 0; j < 8; ++j) s += redq[t][j];
    xqs[t] = s;
  }

  float Ap[OC];
  #pragma unroll
  for (int c = 0; c < OC; ++c) Ap[c] = 1.0f;

  #pragma unroll 1
  for (int chunk = 0; chunk < 4; ++chunk) {
    __syncthreads();   // prev combine's reads of ss/vsd done; stage visible

    for (int i = t; i < OC * 128; i += 256)      // vsd[c][kk] <- VS table
      vsd[i] = VS[(i >> 7) * NP + chunk * 128 + (i & 127)];
    if (t < 128) {
      const int k = chunk * 128 + t;
      wqs[t] = WQ[k]; aps[t] = AP[k]; g2s[t] = G2[k];
    }

    // MFMA: 32x32 tile over K=256, hi/lo 3-pass; W prefetched 4 steps deep
    f32x16 acc;
    #pragma unroll
    for (int i = 0; i < 16; ++i) acc[i] = 0.f;
    const int ptile = chunk * 4 + wave;
    const short8* bH = (const short8*)PWH + (size_t)ptile * 16 * 64 + lane;
    const short8* bL = (const short8*)PWL + (size_t)ptile * 16 * 64 + lane;
    const short8* aH = (const short8*)Ah + lane;
    const short8* aL = (const short8*)Al + lane;

    short8 wbh[4], wbl[4];
    #pragma unroll
    for (int p = 0; p < 4; ++p) { wbh[p] = bH[p * 64]; wbl[p] = bL[p * 64]; }

    #pragma unroll
    for (int step = 0; step < 16; ++step) {
      const short8 ah = aH[step * 64], al = aL[step * 64];
      const short8 bh = wbh[step & 3], bl = wbl[step & 3];
      if (step < 12) {                 // refill ring slot 4 steps ahead
        wbh[step & 3] = bH[(step + 4) * 64];
        wbl[step & 3] = bL[(step + 4) * 64];
      }
      acc = __builtin_amdgcn_mfma_f32_32x32x16_bf16(ah, bh, acc, 0, 0, 0);
      acc = __builtin_amdgcn_mfma_f32_32x32x16_bf16(ah, bl, acc, 0, 0, 0);
      acc = __builtin_amdgcn_mfma_f32_32x32x16_bf16(al, bh, acc, 0, 0, 0);
    }
    __syncthreads();   // vsd/params visible

    // epilogue: s = alphap * exp(-g2 * (0.5*(wq+xq) - dot))
    // C/D layout: col(n)=lane&31, row(m)=(reg&3)+8*(reg>>2)+4*(lane>>5)
    {
      const int   pl  = wave * 32 + (lane & 31);
      const float wqk = wqs[pl], apk = aps[pl], g2k = g2s[pl];
      const int   rb  = 4 * (lane >> 5);
      #pragma unroll
      for (int rg = 0; rg < 16; ++rg) {
        const int   m  = (rg & 3) + 8 * (rg >> 2) + rb;
        const float dv = 0.5f * (wqk + xqs[m]) - acc[rg];
        ss[pl * 33 + m] = apk * __expf(-g2k * dv);
      }
    }
    __syncthreads();   // ss ready

    // combine: thread (cb=t&31, part=t>>5) folds its 16 k's into Ap[21]
    {
      const int cb = t & 31, part = t >> 5;
      float sv[16];
      #pragma unroll
      for (int i = 0; i < 16; ++i) sv[i] = ss[(part * 16 + i) * 33 + cb];
      #pragma unroll
      for (int c = 0; c < OC; ++c) {
        const float* vc = &vsd[c * 128 + part * 16];
        float a = Ap[c];
        #pragma unroll
        for (int q = 0; q < 4; ++q) {
          const float t0 = fmaf(-sv[4*q+0], vc[4*q+0], 1.0f);
          const float t1 = fmaf(-sv[4*q+1], vc[4*q+1], 1.0f);
          const float t2 = fmaf(-sv[4*q+2], vc[4*q+2], 1.0f);
          const float t3 = fmaf(-sv[4*q+3], vc[4*q+3], 1.0f);
          a = a * ((t0 * t1) * (t2 * t3));
        }
        Ap[c] = a;
      }
    }
  }

  // cross-part product reduction (8 partials per (b,c)), normalize, store
  const int cb = t & 31, part = t >> 5;
  __syncthreads();
  if (part >= 4) {
    #pragma unroll
    for (int c = 0; c < OC; ++c) ss[((part - 4) * OC + c) * 33 + cb] = Ap[c];
  }
  __syncthreads();
  if (part < 4) {
    #pragma unroll
    for (int c = 0; c < OC; ++c) Ap[c] *= ss[(part * OC + c) * 33 + cb];
  }
  __syncthreads();
  if (part >= 2 && part < 4) {
    #pragma unroll
    for (int c = 0; c < OC; ++c) ss[((part - 2) * OC + c) * 33 + cb] = Ap[c];
  }
  __syncthreads();
  if (part < 2) {
    #pragma unroll
    for (int c = 0; c < OC; ++c) Ap[c] *= ss[(part * OC + c) * 33 + cb];
  }
  __syncthreads();
  if (part == 1) {
    #pragma unroll
    for (int c = 0; c < OC; ++c) ss[c * 33 + cb] = Ap[c];
  }
  __syncthreads();
  if (part == 0) {
    #pragma unroll
    for (int c = 0; c < OC; ++c) Ap[c] *= ss[c * 33 + cb];
    const float Nv = Ap[NCLS];
    float Ks = Nv;
    #pragma unroll
    for (int c = 0; c < NCLS; ++c) Ks += Ap[c] - Nv;
    const float invk = 1.0f / Ks;
    #pragma unroll
    for (int c = 0; c < NCLS; ++c) ss[c * 33 + cb] = (Ap[c] - Nv) * invk;
    ss[NCLS * 33 + cb] = Nv * invk;
  }
  __syncthreads();
  for (int idx = t; idx < 32 * OC; idx += 256) {
    const int b = idx / OC, c = idx - b * OC;
    OUT[(size_t)tile * 32 * OC + idx] = ss[c * 33 + b];
  }
}

// ---------------- fallback (verified f32 path, used if ws too small) ----------------
#define TBF 64
#define TKF 64
#define DSL 64
#define LDX 68

__device__ __forceinline__ void fma4(const float4 a, const float4 b, float& d) {
  d = fmaf(a.x, b.x, d); d = fmaf(a.y, b.y, d);
  d = fmaf(a.z, b.z, d); d = fmaf(a.w, b.w, d);
}

__global__ __launch_bounds__(256)
void evid_fused(const float* __restrict__ X, const float* __restrict__ Wm,
                const float* __restrict__ BETA, const float* __restrict__ ALPHA,
                const float* __restrict__ GAMMA, float* __restrict__ OUT)
{
  __shared__ __align__(16) float xs[DSL][LDX], wsh[DSL][LDX], ssf[TKF][LDX], vs[OC][LDX];
  __shared__ float xq[TBF], wq[TKF], apch[TKF], g2ch[TKF];
  __shared__ float redx[4][TBF], redw[4][TKF];
  const int t = threadIdx.x, bbase = blockIdx.x * TBF;
  const int tb = t & 15, tk = t >> 4, srow = t >> 4, sdq = t & 15;
  const int cbf = t & 63, part = t >> 6;
  float Ap[OC];
  #pragma unroll
  for (int c = 0; c < OC; ++c) Ap[c] = 1.0f;
  float xqacc = 0.0f;
  for (int chunk = 0; chunk < 8; ++chunk) {
    const int k0 = chunk * TKF;
    __syncthreads();
    if (t < TKF) {
      const int k = k0 + t;
      float bsum = 0.0f;
      #pragma unroll
      for (int c = 0; c < NCLS; ++c) { const float bv = BETA[k*NCLS+c]; bsum = fmaf(bv, bv, bsum); }
      const float binv = 1.0f / bsum;
      #pragma unroll
      for (int c = 0; c < NCLS; ++c) { const float bv = BETA[k*NCLS+c]; vs[c][t] = 1.0f - bv*bv*binv; }
      vs[NCLS][t] = 1.0f;
      apch[t] = 0.99f / (1.0f + expf(-ALPHA[k]));
      const float gv = GAMMA[k]; g2ch[t] = gv * gv;
    }
    float acc[4][4] = {};
    float wqacc = 0.0f;
    for (int sl = 0; sl < 4; ++sl) {
      const int d0 = sl * DSL;
      __syncthreads();
      #pragma unroll
      for (int p = 0; p < 4; ++p) {
        const int r = srow + 16 * p;
        *(float4*)&xs [r][4*sdq] = *(const float4*)&X [(size_t)(bbase + r)*ND + d0 + 4*sdq];
        *(float4*)&wsh[r][4*sdq] = *(const float4*)&Wm[(size_t)(k0    + r)*ND + d0 + 4*sdq];
      }
      __syncthreads();
      #pragma unroll
      for (int m = 0; m < 4; ++m) {
        const float4 v = *(const float4*)&wsh[cbf][part*16 + 4*m];
        wqacc = fmaf(v.x,v.x, fmaf(v.y,v.y, fmaf(v.z,v.z, fmaf(v.w,v.w, wqacc))));
      }
      if (chunk == 0) {
        #pragma unroll
        for (int m = 0; m < 4; ++m) {
          const float4 v = *(const float4*)&xs[cbf][part*16 + 4*m];
          xqacc = fmaf(v.x,v.x, fmaf(v.y,v.y, fmaf(v.z,v.z, fmaf(v.w,v.w, xqacc))));
        }
      }
      #pragma unroll
      for (int dq = 0; dq < 16; ++dq) {
        const float4 xa0 = *(const float4*)&xs [tb +  0][4*dq];
        const float4 xa1 = *(const float4*)&xs [tb + 16][4*dq];
        const float4 xa2 = *(const float4*)&xs [tb + 32][4*dq];
        const float4 xa3 = *(const float4*)&xs [tb + 48][4*dq];
        const float4 wb0 = *(const float4*)&wsh[tk +  0][4*dq];
        const float4 wb1 = *(const float4*)&wsh[tk + 16][4*dq];
        const float4 wb2 = *(const float4*)&wsh[tk + 32][4*dq];
        const float4 wb3 = *(const float4*)&wsh[tk + 48][4*dq];
        fma4(xa0, wb0, acc[0][0]); fma4(xa0, wb1, acc[0][1]); fma4(xa0, wb2, acc[0][2]); fma4(xa0, wb3, acc[0][3]);
        fma4(xa1, wb0, acc[1][0]); fma4(xa1, wb1, acc[1][1]); fma4(xa1, wb2, acc[1][2]); fma4(xa1, wb3, acc[1][3]);
        fma4(xa2, wb0, acc[2][0]); fma4(xa2, wb1, acc[2][1]); fma4(xa2, wb2, acc[2][2]); fma4(xa2, wb3, acc[2][3]);
        fma4(xa3, wb0, acc[3][0]); fma4(xa3, wb1, acc[3][1]); fma4(xa3, wb2, acc[3][2]); fma4(xa3, wb3, acc[3][3]);
      }
    }
    redw[part][cbf] = wqacc;
    if (chunk == 0) redx[part][cbf] = xqacc;
    __syncthreads();
    if (t < TKF) {
      wq[t] = redw[0][t] + redw[1][t] + redw[2][t] + redw[3][t];
      if (chunk == 0) xq[t] = redx[0][t] + redx[1][t] + redx[2][t] + redx[3][t];
    }
    __syncthreads();
    #pragma unroll
    for (int j = 0; j < 4; ++j) {
      const int kj = tk + 16 * j;
      const float wqk = wq[kj], ap = apch[kj], g2 = g2ch[kj];
      #pragma unroll
      for (int i = 0; i < 4; ++i) {
        const int bi = tb + 16 * i;
        ssf[kj][bi] = ap * expf(-g2 * (0.5f*(wqk + xq[bi]) - acc[i][j]));
      }
    }
    __syncthreads();
    {
      float sv[16];
      #pragma unroll
      for (int m = 0; m < 16; ++m) sv[m] = ssf[16*part + m][cbf];
      #pragma unroll
      for (int c = 0; c < OC; ++c) {
        float a = Ap[c];
        #pragma unroll
        for (int mq = 0; mq < 4; ++mq) {
          const float4 vv = *(const float4*)&vs[c][16*part + 4*mq];
          const float t0 = fmaf(-sv[4*mq+0], vv.x, 1.0f);
          const float t1 = fmaf(-sv[4*mq+1], vv.y, 1.0f);
          const float t2 = fmaf(-sv[4*mq+2], vv.z, 1.0f);
          const float t3 = fmaf(-sv[4*mq+3], vv.w, 1.0f);
          a = a * ((t0*t1)*(t2*t3));
        }
        Ap[c] = a;
      }
    }
  }
  __syncthreads();
  if (part >= 2) {
    #pragma unroll
    for (int c = 0; c < OC; ++c) ssf[(part-2)*OC + c][cbf] = Ap[c];
  }
  __syncthreads();
  if (part < 2) {
    #pragma unroll
    for (int c = 0; c < OC; ++c) Ap[c] *= ssf[part*OC + c][cbf];
  }
  __syncthreads();
  if (part == 1) {
    #pragma unroll
    for (int c = 0; c < OC; ++c) ssf[c][cbf] = Ap[c];
  }
  __syncthreads();
  if (part == 0) {
    #pragma unroll
    for (int c = 0; c < OC; ++c) Ap[c] *= ssf[c][cbf];
    const float Nv = Ap[NCLS];
    float Ks = Nv;
    #pragma unroll
    for (int c = 0; c < NCLS; ++c) Ks += Ap[c] - Nv;
    const float invk = 1.0f / Ks;
    #pragma unroll
    for (int c = 0; c < NCLS; ++c) ssf[c][cbf] = (Ap[c] - Nv) * invk;
    ssf[NCLS][cbf] = Nv * invk;
  }
  __syncthreads();
  for (int idx = t; idx < TBF*OC; idx += 256) {
    const int b = idx / OC, c = idx - b*OC;
    OUT[(size_t)bbase*OC + idx] = ssf[c][b];
  }
}

extern "C" void kernel_launch(void* const* d_in, const int* in_sizes, int n_in,
                              void* d_out, int out_size, void* d_ws, size_t ws_size,
                              hipStream_t stream) {
  (void)in_sizes; (void)n_in; (void)out_size;
  const float* X     = (const float*)d_in[0];
  const float* Wm    = (const float*)d_in[1];
  const float* BETA  = (const float*)d_in[2];
  const float* ALPHA = (const float*)d_in[3];
  const float* GAMMA = (const float*)d_in[4];
  float* OUT = (float*)d_out;

  if (ws_size < WS_NEED) {   // fallback: verified f32 path
    hipLaunchKernelGGL(evid_fused, dim3(NBATCH/TBF), dim3(256), 0, stream,
                       X, Wm, BETA, ALPHA, GAMMA, OUT);
    return;
  }
  char* ws = (char*)d_ws;
  unsigned short* PWH = (unsigned short*)(ws + OFF_PWH);
  unsigned short* PWL = (unsigned short*)(ws + OFF_PWL);
  float* VS = (float*)(ws + OFF_VS);
  float* WQ = (float*)(ws + OFF_WQ);
  float* AP = (float*)(ws + OFF_AP);
  float* G2 = (float*)(ws + OFF_G2);

  hipLaunchKernelGGL(prep, dim3(66), dim3(256), 0, stream,
                     Wm, BETA, ALPHA, GAMMA, PWH, PWL, WQ, VS, AP, G2);
  hipLaunchKernelGGL(evid_main, dim3(NBATCH/32), dim3(256), 0, stream,
                     X, PWH, PWL, VS, WQ, AP, G2, OUT);
}